// Round 4
// baseline (804.831 us; speedup 1.0000x reference)
//
#include <hip/hip_runtime.h>
#include <stdint.h>

#define D_MODEL   1024
#define D_STATE   64
#define D_INNER   2048
#define NHEADS    32
#define CONV_DIM  2176
#define D_IN_PROJ 4256
#define NPAD1     4352   // 34*128, padded N for in_proj GEMM (17*256)
#define LSEQ      4096
#define BL        8192   // B*L
#define NCHUNK    32     // scan time-chunks
#define TCH       128    // steps per chunk
#define EPS       1e-5f

typedef __attribute__((ext_vector_type(8))) _Float16 f16x8;
typedef __attribute__((ext_vector_type(4))) _Float16 f16x4;
typedef __attribute__((ext_vector_type(4))) float f32x4;

__device__ __forceinline__ void load_lds16(const void* g, void* l) {
  __builtin_amdgcn_global_load_lds((const __attribute__((address_space(1))) void*)g,
                                   (__attribute__((address_space(3))) void*)l, 16, 0, 0);
}

// ---------------- weight casts: fp32 -> fp16 ----------------
__global__ __launch_bounds__(256) void cvt_w1_kernel(const float* __restrict__ w,
                                                     _Float16* __restrict__ o) {
  size_t idx = (size_t)blockIdx.x * 256 + threadIdx.x;   // over 2*4352*1024
  int k = idx & 1023;
  size_t nr = idx >> 10;
  int layer = (int)(nr / NPAD1);
  int n = (int)(nr % NPAD1);
  float v = (n < D_IN_PROJ) ? w[((size_t)layer * D_IN_PROJ + n) * 1024 + k] : 0.f;
  o[idx] = (_Float16)v;
}
__global__ __launch_bounds__(256) void cvt_w2_kernel(const float* __restrict__ w,
                                                     _Float16* __restrict__ o) {
  size_t idx = (size_t)blockIdx.x * 256 + threadIdx.x;   // over 2*1024*2048
  o[idx] = (_Float16)w[idx];
}

// ---------------- layernorm (row of 1024), fp32 in -> fp16 out ----------------
__global__ __launch_bounds__(256) void ln_kernel(const float* __restrict__ x,
                                                 const float* __restrict__ w,
                                                 const float* __restrict__ b,
                                                 _Float16* __restrict__ o) {
  int row = blockIdx.x, tid = threadIdx.x;
  const float* xr = x + (size_t)row * D_MODEL;
  float4 v = *(const float4*)(xr + tid * 4);
  float s = v.x + v.y + v.z + v.w;
  float q = v.x * v.x + v.y * v.y + v.z * v.z + v.w * v.w;
  for (int off = 1; off < 64; off <<= 1) { s += __shfl_xor(s, off); q += __shfl_xor(q, off); }
  __shared__ float rs[4], rq[4];
  int wave = tid >> 6, lane = tid & 63;
  if (lane == 0) { rs[wave] = s; rq[wave] = q; }
  __syncthreads();
  s = rs[0] + rs[1] + rs[2] + rs[3];
  q = rq[0] + rq[1] + rq[2] + rq[3];
  float mean = s * (1.f / D_MODEL);
  float var = q * (1.f / D_MODEL) - mean * mean;
  float rstd = rsqrtf(var + EPS);
  int c = tid * 4;
  f16x4 ov;
  ov[0] = (_Float16)((v.x - mean) * rstd * w[c + 0] + b[c + 0]);
  ov[1] = (_Float16)((v.y - mean) * rstd * w[c + 1] + b[c + 1]);
  ov[2] = (_Float16)((v.z - mean) * rstd * w[c + 2] + b[c + 2]);
  ov[3] = (_Float16)((v.w - mean) * rstd * w[c + 3] + b[c + 3]);
  *(f16x4*)(o + (size_t)row * D_MODEL + c) = ov;
}

// ---------------- fp16 GEMM, C[m,n] = sum_k A[m,k]*B[n,k] ----------------
// 256x256 tile, BK=32, 8 waves (2M x 4N; wave tile 128x64, acc 8x4 frags).
// PHASED schedule (T3+T4+T5): per K-tile, 2 phases = one 64-row M-quadrant x
// full N each (16 MFMA). Each phase co-issues {ds_read frags || stage a half
// of tile t+3} before its barrier; ONE counted vmcnt(8) per iteration (placed
// a full barrier before the first ds_read of the buffer it protects). 4 LDS
// K-tile buffers (128 KB, 1 block/CU). Zero-conflict slot-XOR swizzle
// (slot ^= (row>>1)&3) on BOTH sides (rule #21). XCD-chunked band raster.
template <int MODE>
__global__ __launch_bounds__(512, 2) void gemm_f16_kernel(
    const _Float16* __restrict__ A, int lda,
    const _Float16* __restrict__ Bw, int K, int NBN,
    _Float16* __restrict__ Zb, _Float16* __restrict__ XPRE, float* __restrict__ AUX,
    float* __restrict__ Cf, const float* __restrict__ resid) {
  __shared__ _Float16 lA[4][256 * 32];
  __shared__ _Float16 lB[4][256 * 32];
  int tid = threadIdx.x;
  int wv = tid >> 6, lane = tid & 63;
  // XCD-chunked bijection (nwg % 8 == 0); chunk = contiguous bm band
  int nwg = gridDim.x;
  int cpx = nwg >> 3;
  int wg = ((int)blockIdx.x & 7) * cpx + ((int)blockIdx.x >> 3);
  int bm = wg / NBN, bn = wg % NBN;

  const int wm = (wv >> 2) * 128;     // M half: 0 or 128
  const int wn = (wv & 3) * 64;       // N quarter
  const int fr = lane & 15;
  const int s4 = lane >> 4;           // 16B slot within 64B row
  size_t aoff = (size_t)(bm * 256) * lda;
  size_t boff = (size_t)(bn * 256) * K;

  const int srow = tid >> 2;          // staging: 4 threads/row (64B)
  const int sslot = tid & 3;

  f32x4 acc[8][4];
  f32x4 zero = {0.f, 0.f, 0.f, 0.f};
#pragma unroll
  for (int i = 0; i < 8; ++i)
#pragma unroll
    for (int j = 0; j < 4; ++j) acc[i][j] = zero;

  auto stageA = [&](int kt, int buf) {
#pragma unroll
    for (int rr = 0; rr < 2; ++rr) {
      int row = rr * 128 + srow;
      int col = kt * 32 + ((sslot ^ ((row >> 1) & 3)) << 3);   // pre-swizzled source
      load_lds16(A + aoff + (size_t)row * lda + col, &lA[buf][row * 32 + sslot * 8]);
    }
  };
  auto stageB = [&](int kt, int buf) {
#pragma unroll
    for (int rr = 0; rr < 2; ++rr) {
      int row = rr * 128 + srow;
      int col = kt * 32 + ((sslot ^ ((row >> 1) & 3)) << 3);
      load_lds16(Bw + boff + (size_t)row * K + col, &lB[buf][row * 32 + sslot * 8]);
    }
  };

  int nk = K >> 5;
  stageA(0, 0); stageB(0, 0);
  stageA(1, 1); stageB(1, 1);
  stageA(2, 2); stageB(2, 2);                     // 12 vm-ops in flight
  asm volatile("s_waitcnt vmcnt(8)" ::: "memory"); // tile 0 complete
  __builtin_amdgcn_s_barrier();

  for (int t = 0; t < nk; ++t) {
    int buf = t & 3;
    int pbuf = (t + 3) & 3;                       // == (t-1)&3: consumed last iter
    bool pf = (t + 3 < nk);
    f16x8 af[4], bf[4];
    // ---- phase 0: M-quadrant 0 x full N ----
#pragma unroll
    for (int j = 0; j < 4; ++j) {
      int R = wn + j * 16 + fr;
      bf[j] = *(const f16x8*)&lB[buf][R * 32 + ((s4 ^ ((R >> 1) & 3)) << 3)];
    }
#pragma unroll
    for (int i = 0; i < 4; ++i) {
      int R = wm + i * 16 + fr;
      af[i] = *(const f16x8*)&lA[buf][R * 32 + ((s4 ^ ((R >> 1) & 3)) << 3)];
    }
    if (pf) stageA(t + 3, pbuf);
    __builtin_amdgcn_s_barrier();
    asm volatile("s_waitcnt lgkmcnt(0)" ::: "memory");
    __builtin_amdgcn_sched_barrier(0);
    __builtin_amdgcn_s_setprio(1);
#pragma unroll
    for (int i = 0; i < 4; ++i)
#pragma unroll
      for (int j = 0; j < 4; ++j)
        acc[i][j] = __builtin_amdgcn_mfma_f32_16x16x32_f16(af[i], bf[j], acc[i][j], 0, 0, 0);
    __builtin_amdgcn_s_setprio(0);
    __builtin_amdgcn_sched_barrier(0);
    __builtin_amdgcn_s_barrier();
    // ---- phase 1: M-quadrant 1 x full N (reuse bf) ----
#pragma unroll
    for (int i = 0; i < 4; ++i) {
      int R = wm + 64 + i * 16 + fr;
      af[i] = *(const f16x8*)&lA[buf][R * 32 + ((s4 ^ ((R >> 1) & 3)) << 3)];
    }
    if (pf) stageB(t + 3, pbuf);
    if (t + 1 < nk) {
      int rem = nk - 2 - t;                       // tiles beyond t+1 still in flight
      if (rem >= 2)      asm volatile("s_waitcnt vmcnt(8)" ::: "memory");
      else if (rem == 1) asm volatile("s_waitcnt vmcnt(4)" ::: "memory");
      else               asm volatile("s_waitcnt vmcnt(0)" ::: "memory");
    }
    __builtin_amdgcn_s_barrier();                 // all waves confirmed tile t+1
    asm volatile("s_waitcnt lgkmcnt(0)" ::: "memory");
    __builtin_amdgcn_sched_barrier(0);
    __builtin_amdgcn_s_setprio(1);
#pragma unroll
    for (int i = 0; i < 4; ++i)
#pragma unroll
      for (int j = 0; j < 4; ++j)
        acc[4 + i][j] = __builtin_amdgcn_mfma_f32_16x16x32_f16(af[i], bf[j], acc[4 + i][j], 0, 0, 0);
    __builtin_amdgcn_s_setprio(0);
    __builtin_amdgcn_sched_barrier(0);
    __builtin_amdgcn_s_barrier();
  }

  int r0 = (lane >> 4) * 4;
  int cc = lane & 15;
#pragma unroll
  for (int i = 0; i < 8; ++i) {
#pragma unroll
    for (int j = 0; j < 4; ++j) {
      int col = bn * 256 + wn + j * 16 + cc;
#pragma unroll
      for (int r = 0; r < 4; ++r) {
        size_t row = (size_t)(bm * 256 + wm + i * 16 + r0 + r);
        float v = acc[i][j][r];
        if constexpr (MODE == 0) {
          if (col < 2048)       Zb[row * 2048 + col] = (_Float16)v;
          else if (col < 4096)  XPRE[row * 2048 + (col - 2048)] = (_Float16)v;
          else if (col < 4256)  AUX[row * 160 + (col - 4096)] = v;
        } else {
          size_t idx = row * 1024 + col;
          Cf[idx] = v + resid[idx];
        }
      }
    }
  }
}

// ---------------- fused dt: softplus(dt_raw+dt_bias), dta=dt*A, chunk cumsum ----------------
// one block (128 thr) per (h,b,chunk): wave shuffle-scan + cross-wave fixup
__global__ __launch_bounds__(128) void dtlc_kernel(const float* __restrict__ aux,
                                                   const float* __restrict__ dtb,
                                                   const float* __restrict__ alog,
                                                   float* __restrict__ dtt,
                                                   float* __restrict__ lco) {
  int bid = blockIdx.x;    // 2048 = (h,b,chunk)
  int h = bid >> 6, b = (bid >> 5) & 1, ct = bid & 31;
  int tid = threadIdx.x, lane = tid & 63;
  int l = b * LSEQ + ct * TCH + tid;                       // row in BL
  float A = -__expf(alog[h]);                              // A = -exp(A_log)
  float v = aux[(size_t)l * 160 + 128 + h] + dtb[h];
  float sp = (v > 20.f) ? v : log1pf(expf(v));
  size_t base = (size_t)h * BL + b * LSEQ + ct * TCH;
  dtt[base + tid] = sp;
  float d = sp * A;                                        // log per-step decay <= 0
#pragma unroll
  for (int off = 1; off < 64; off <<= 1) {
    float o = __shfl_up(d, off);
    if (lane >= off) d += o;
  }
  __shared__ float tot;
  if (tid == 63) tot = d;
  __syncthreads();
  if (tid >= 64) d += tot;
  lco[base + tid] = d;
}

// ---------------- causal depthwise conv (width 4) + bias + silu ----------------
// tiled: 16 timesteps per block with rolling register window
__global__ __launch_bounds__(256) void conv_kernel(const _Float16* __restrict__ xpre,
                                                   const float* __restrict__ aux,
                                                   const float* __restrict__ cw,
                                                   const float* __restrict__ cb,
                                                   _Float16* __restrict__ xh,
                                                   float* __restrict__ Bo,
                                                   float* __restrict__ Co) {
  int c = blockIdx.y * 256 + threadIdx.x;
  if (c >= CONV_DIM) return;
  int l0 = blockIdx.x * 16;                 // 512 blocks in x; 4096 % 16 == 0
  float w0 = cw[c * 4 + 0], w1 = cw[c * 4 + 1], w2 = cw[c * 4 + 2], w3 = cw[c * 4 + 3];
  float bias = cb[c];
  bool isx = (c < 2048);
  auto ldx = [&](int l) -> float {
    return isx ? (float)xpre[(size_t)l * 2048 + c] : aux[(size_t)l * 160 + (c - 2048)];
  };
  float a0 = 0.f, a1 = 0.f, a2 = 0.f;
  if ((l0 & 4095) != 0) { a0 = ldx(l0 - 3); a1 = ldx(l0 - 2); a2 = ldx(l0 - 1); }
#pragma unroll
  for (int t = 0; t < 16; ++t) {
    int l = l0 + t;
    float a3 = ldx(l);
    float acc = bias + a0 * w0 + a1 * w1 + a2 * w2 + a3 * w3;
    acc = acc / (1.f + __expf(-acc));       // silu
    if (isx)
      xh[(size_t)l * 2048 + c] = (_Float16)acc;
    else if (c < 2112)
      Bo[(size_t)l * 64 + (c - 2048)] = acc;
    else
      Co[(size_t)l * 64 + (c - 2112)] = acc;
    a0 = a1; a1 = a2; a2 = a3;
  }
}

// ---------------- tiled transpose: XH[8192][2048] f16 -> XT[2048][8192] f16 ----------------
__global__ __launch_bounds__(256) void transpose_x_kernel(const _Float16* __restrict__ xh,
                                                          _Float16* __restrict__ xt) {
  __shared__ _Float16 T[64 * 65];
  int c0 = blockIdx.x * 64;
  int l0 = blockIdx.y * 64;
  int tid = threadIdx.x;
  int rr = tid >> 3, g8 = tid & 7;
#pragma unroll
  for (int p = 0; p < 2; ++p) {
    int l = p * 32 + rr;
    f16x8 v = *(const f16x8*)&xh[(size_t)(l0 + l) * 2048 + c0 + g8 * 8];
#pragma unroll
    for (int j = 0; j < 8; ++j) T[l * 65 + g8 * 8 + j] = v[j];
  }
  __syncthreads();
#pragma unroll
  for (int p = 0; p < 2; ++p) {
    int c = p * 32 + rr;
    f16x8 v;
#pragma unroll
    for (int j = 0; j < 8; ++j) v[j] = T[(g8 * 8 + j) * 65 + c];
    *(f16x8*)&xt[(size_t)(c0 + c) * 8192 + l0 + g8 * 8] = v;
  }
}

// ---------------- tiled transpose: BC[8192][64] f32 -> BT[64][8192] f16 ----------------
__global__ __launch_bounds__(256) void transpose_b_kernel(const float* __restrict__ bc,
                                                          _Float16* __restrict__ bt) {
  __shared__ _Float16 T[64 * 65];
  int l0 = blockIdx.x * 64;
  int tid = threadIdx.x;
  int rr4 = tid >> 4, cl = tid & 15;
#pragma unroll
  for (int p = 0; p < 4; ++p) {
    int l = p * 16 + rr4;
    float4 v = *(const float4*)&bc[(size_t)(l0 + l) * 64 + cl * 4];
    T[l * 65 + cl * 4 + 0] = (_Float16)v.x;
    T[l * 65 + cl * 4 + 1] = (_Float16)v.y;
    T[l * 65 + cl * 4 + 2] = (_Float16)v.z;
    T[l * 65 + cl * 4 + 3] = (_Float16)v.w;
  }
  __syncthreads();
  int rr = tid >> 3, g8 = tid & 7;
#pragma unroll
  for (int p = 0; p < 2; ++p) {
    int n = p * 32 + rr;
    f16x8 v;
#pragma unroll
    for (int j = 0; j < 8; ++j) v[j] = T[(g8 * 8 + j) * 65 + n];
    *(f16x8*)&bt[(size_t)n * 8192 + l0 + g8 * 8] = v;
  }
}

// ---------------- SSD pass 1 (MFMA): per-chunk local end-state ----------------
// S_loc[p][n] = sum_t (dt_t*exp(lc_last-lc_t)*X[t,p]) * B[t,n]; grid 2048 = (b,h,chunk).
__global__ __launch_bounds__(256) void scan_state_kernel(
    const _Float16* __restrict__ xt, const _Float16* __restrict__ bt,
    const float* __restrict__ lc, const float* __restrict__ dtt,
    float* __restrict__ cs) {
  int bid = blockIdx.x;
  int chunk = bid & 31, h = (bid >> 5) & 31, b = bid >> 10;
  int tid = threadIdx.x;
  size_t gb = (size_t)b * LSEQ + chunk * TCH;
  size_t cdb = (size_t)h * BL + gb;
  __shared__ _Float16 xtl[64 * 128];   // [p][t], swizzled
  __shared__ _Float16 btl[64 * 128];   // [n][t], swizzled
  __shared__ float ldsW[128];
  if (tid < 128) ldsW[tid] = dtt[cdb + tid] * __expf(lc[cdb + 127] - lc[cdb + tid]);
  __syncthreads();
  int rr = tid >> 4, cl = tid & 15;
#pragma unroll
  for (int p = 0; p < 4; ++p) {
    int row = p * 16 + rr;
    f16x8 v = *(const f16x8*)&xt[(size_t)(h * 64 + row) * BL + gb + cl * 8];
    f16x8 bv = *(const f16x8*)&bt[(size_t)row * BL + gb + cl * 8];
    f16x8 sv;
#pragma unroll
    for (int j = 0; j < 8; ++j) sv[j] = (_Float16)((float)v[j] * ldsW[cl * 8 + j]);
    int byo = (row * 256 + cl * 16) ^ ((row & 7) << 4);
    *(f16x8*)((char*)xtl + byo) = sv;
    *(f16x8*)((char*)btl + byo) = bv;
  }
  __syncthreads();
  int wv = tid >> 6, lane = tid & 63;
  int fr = lane & 15, fk = (lane >> 4) * 8, r0 = (lane >> 4) * 4, cc = lane & 15;
  int swz = (fr & 7) << 4;
  f32x4 acc[4];
  f32x4 zero = {0.f, 0.f, 0.f, 0.f};
#pragma unroll
  for (int j = 0; j < 4; ++j) acc[j] = zero;
#pragma unroll
  for (int k0 = 0; k0 < 128; k0 += 32) {
    f16x8 af = *(const f16x8*)((char*)xtl + (((wv * 16 + fr) * 256 + (k0 + fk) * 2) ^ swz));
#pragma unroll
    for (int j = 0; j < 4; ++j) {
      f16x8 bf = *(const f16x8*)((char*)btl + (((j * 16 + fr) * 256 + (k0 + fk) * 2) ^ swz));
      acc[j] = __builtin_amdgcn_mfma_f32_16x16x32_f16(af, bf, acc[j], 0, 0, 0);
    }
  }
  size_t cbase = (((size_t)(b * 32 + h) * 32) + chunk) * 4096;
#pragma unroll
  for (int j = 0; j < 4; ++j)
#pragma unroll
    for (int r = 0; r < 4; ++r)
      cs[cbase + (wv * 16 + r0 + r) * 64 + j * 16 + cc] = acc[j][r];
}

// ---------------- scan pass 2: prefix over chunks, IN PLACE (E_c -> S_{c-1}) ----------------
__global__ __launch_bounds__(256) void scan_p2_kernel(float* __restrict__ cs,
                                                      const float* __restrict__ lc) {
  int bid = blockIdx.x;    // (b,h,pq)
  int b = bid >> 7, h = (bid >> 2) & 31, pq = bid & 3;
  int tid = threadIdx.x;
  size_t base = ((size_t)(b * 32 + h) * 32) * 4096 + (size_t)(pq * 256 + tid) * 4;
  const float* lcd = lc + (size_t)h * BL + b * LSEQ;
  float4 s = {0.f, 0.f, 0.f, 0.f};
  for (int c = 0; c < NCHUNK; ++c) {
    size_t idx = base + (size_t)c * 4096;
    float4 e = *(const float4*)&cs[idx];
    float P = __expf(lcd[c * TCH + TCH - 1]);   // total decay of chunk c
    *(float4*)&cs[idx] = s;                     // prefix state entering chunk c
    s.x = e.x + P * s.x;
    s.y = e.y + P * s.y;
    s.z = e.z + P * s.z;
    s.w = e.w + P * s.w;
  }
}

// ---------------- SSD pass 3 (MFMA): Y = (mask o C.B^T).X + exp(lc)*(C.Sprev^T) -----------
// mask[t,s] = exp(lc_t - lc_s)*dt_s for s<=t; diag += D_h (absorbs skip). grid 2048.
__global__ __launch_bounds__(256) void scan_y_kernel(
    const _Float16* __restrict__ xt, const float* __restrict__ Cc,
    const float* __restrict__ Bc, const float* __restrict__ cs,
    const float* __restrict__ lc, const float* __restrict__ dtt,
    const float* __restrict__ Dv, float* __restrict__ y) {
  int bid = blockIdx.x;
  int chunk = bid & 31, h = (bid >> 5) & 31, b = bid >> 10;
  int tid = threadIdx.x;
  size_t gb = (size_t)b * LSEQ + chunk * TCH;
  size_t cdb = (size_t)h * BL + gb;

  __shared__ _Float16 uCB[2 * 128 * 64];   // C [128][64] | B [128][64]; then P [128][128]
  __shared__ _Float16 xtl[64 * 128];       // X^T [p][t]
  __shared__ _Float16 spl[64 * 64];        // Sprev [p][n]
  __shared__ float ldsLc[128];
  __shared__ float ldsDt[128];
  _Float16* Cl = uCB;
  _Float16* Bl = uCB + 128 * 64;
  _Float16* Pl = uCB;

  int rr = tid >> 4, cl = tid & 15;
#pragma unroll
  for (int p = 0; p < 8; ++p) {
    int row = p * 16 + rr;
    float4 cv = *(const float4*)&Cc[(gb + row) * 64 + cl * 4];
    float4 bv = *(const float4*)&Bc[(gb + row) * 64 + cl * 4];
    f16x4 ch = {(_Float16)cv.x, (_Float16)cv.y, (_Float16)cv.z, (_Float16)cv.w};
    f16x4 bh = {(_Float16)bv.x, (_Float16)bv.y, (_Float16)bv.z, (_Float16)bv.w};
    int byo = (row * 128 + cl * 8) ^ ((row & 7) << 4);
    *(f16x4*)((char*)Cl + byo) = ch;
    *(f16x4*)((char*)Bl + byo) = bh;
  }
  size_t cbase = (((size_t)(b * 32 + h) * 32) + chunk) * 4096;
#pragma unroll
  for (int p = 0; p < 4; ++p) {
    int row = p * 16 + rr;
    f16x8 v = *(const f16x8*)&xt[(size_t)(h * 64 + row) * BL + gb + cl * 8];
    int byo = (row * 256 + cl * 16) ^ ((row & 7) << 4);
    *(f16x8*)((char*)xtl + byo) = v;
    float4 sv = *(const float4*)&cs[cbase + row * 64 + cl * 4];
    f16x4 sh = {(_Float16)sv.x, (_Float16)sv.y, (_Float16)sv.z, (_Float16)sv.w};
    int byo2 = (row * 128 + cl * 8) ^ ((row & 7) << 4);
    *(f16x4*)((char*)spl + byo2) = sh;
  }
  if (tid < 128) { ldsLc[tid] = lc[cdb + tid]; ldsDt[tid] = dtt[cdb + tid]; }
  __syncthreads();

  int wv = tid >> 6, lane = tid & 63;
  int fr = lane & 15, fk = (lane >> 4) * 8, r0 = (lane >> 4) * 4, cc = lane & 15;
  int tb = wv * 32;                 // this wave's 32 output rows (t)
  int swz = (fr & 7) << 4;

  f32x4 accY[2][4];                 // [t-tile][p-tile]
  f32x4 accS[2][8];                 // [t-tile][s-tile]
  f32x4 zero = {0.f, 0.f, 0.f, 0.f};
#pragma unroll
  for (int i = 0; i < 2; ++i) {
#pragma unroll
    for (int j = 0; j < 4; ++j) accY[i][j] = zero;
#pragma unroll
    for (int j = 0; j < 8; ++j) accS[i][j] = zero;
  }

  // phase 1+2: inter-term C.Sprev^T and S1 = C.B^T (K = n = 64)
#pragma unroll
  for (int k0 = 0; k0 < 64; k0 += 32) {
    f16x8 ac[2];
#pragma unroll
    for (int i = 0; i < 2; ++i)
      ac[i] = *(const f16x8*)((char*)Cl + (((tb + i * 16 + fr) * 128 + (k0 + fk) * 2) ^ swz));
#pragma unroll
    for (int j = 0; j < 4; ++j) {
      f16x8 bs = *(const f16x8*)((char*)spl + (((j * 16 + fr) * 128 + (k0 + fk) * 2) ^ swz));
#pragma unroll
      for (int i = 0; i < 2; ++i)
        accY[i][j] = __builtin_amdgcn_mfma_f32_16x16x32_f16(ac[i], bs, accY[i][j], 0, 0, 0);
    }
#pragma unroll
    for (int j = 0; j < 8; ++j) {
      f16x8 bb = *(const f16x8*)((char*)Bl + (((j * 16 + fr) * 128 + (k0 + fk) * 2) ^ swz));
#pragma unroll
      for (int i = 0; i < 2; ++i)
        accS[i][j] = __builtin_amdgcn_mfma_f32_16x16x32_f16(ac[i], bb, accS[i][j], 0, 0, 0);
    }
  }

  // scale inter-term by exp(lc_t)
  float lct[2][4];
#pragma unroll
  for (int i = 0; i < 2; ++i)
#pragma unroll
    for (int r = 0; r < 4; ++r) lct[i][r] = ldsLc[tb + i * 16 + r0 + r];
#pragma unroll
  for (int i = 0; i < 2; ++i)
#pragma unroll
    for (int r = 0; r < 4; ++r) {
      float sc = __expf(lct[i][r]);
#pragma unroll
      for (int j = 0; j < 4; ++j) accY[i][j][r] *= sc;
    }

  __syncthreads();   // all waves done reading Cl/Bl/spl before P overlays C|B
  float Dh = Dv[h];
#pragma unroll
  for (int i = 0; i < 2; ++i)
#pragma unroll
    for (int jj = 0; jj < 8; ++jj) {
      int s = jj * 16 + cc;
      float lcs = ldsLc[s];
      float dts = ldsDt[s];
#pragma unroll
      for (int r = 0; r < 4; ++r) {
        int t = tb + i * 16 + r0 + r;
        float v = 0.f;
        if (s <= t) v = accS[i][jj][r] * __expf(lct[i][r] - lcs) * dts;
        if (s == t) v += Dh;                       // skip term: P diag += D_h
        int byo = (t * 256 + s * 2) ^ ((t & 7) << 4);
        *(_Float16*)((char*)Pl + byo) = (_Float16)v;
      }
    }
  __syncthreads();

  // phase 4: Y += P @ X  (K = s = 128)
#pragma unroll
  for (int k0 = 0; k0 < 128; k0 += 32) {
    f16x8 ap[2];
#pragma unroll
    for (int i = 0; i < 2; ++i)
      ap[i] = *(const f16x8*)((char*)Pl + (((tb + i * 16 + fr) * 256 + (k0 + fk) * 2) ^ swz));
#pragma unroll
    for (int j = 0; j < 4; ++j) {
      f16x8 bx = *(const f16x8*)((char*)xtl + (((j * 16 + fr) * 256 + (k0 + fk) * 2) ^ swz));
#pragma unroll
      for (int i = 0; i < 2; ++i)
        accY[i][j] = __builtin_amdgcn_mfma_f32_16x16x32_f16(ap[i], bx, accY[i][j], 0, 0, 0);
    }
  }

#pragma unroll
  for (int i = 0; i < 2; ++i)
#pragma unroll
    for (int j = 0; j < 4; ++j)
#pragma unroll
      for (int r = 0; r < 4; ++r) {
        int t = tb + i * 16 + r0 + r;
        y[(gb + t) * 2048 + h * 64 + j * 16 + cc] = accY[i][j][r];
      }
}

// ---------------- gate (y * silu(z)) + RMSNorm * rms_w -> fp16 G, IN PLACE over Zb ----------
__global__ __launch_bounds__(256) void gate_rms_kernel(const float* __restrict__ yf,
                                                       const _Float16* __restrict__ zb,
                                                       const float* __restrict__ rw,
                                                       _Float16* __restrict__ g) {
  int row = blockIdx.x, tid = threadIdx.x;
  const float* yr = yf + (size_t)row * D_INNER;
  const _Float16* zr = zb + (size_t)row * D_INNER;
  float gv[8];
  float q = 0.f;
#pragma unroll
  for (int u = 0; u < 8; ++u) {
    int c = u * 256 + tid;
    float yv = yr[c];
    float zv = (float)zr[c];
    float t = yv * (zv / (1.f + __expf(-zv)));
    gv[u] = t;
    q += t * t;
  }
  for (int off = 1; off < 64; off <<= 1) q += __shfl_xor(q, off);
  __shared__ float rq[4];
  if ((tid & 63) == 0) rq[tid >> 6] = q;
  __syncthreads();    // all reads of this row are done before writes below
  q = rq[0] + rq[1] + rq[2] + rq[3];
  float scale = rsqrtf(q * (1.f / D_INNER) + EPS);
  _Float16* gr = g + (size_t)row * D_INNER;
#pragma unroll
  for (int u = 0; u < 8; ++u) {
    int c = u * 256 + tid;
    gr[c] = (_Float16)(gv[u] * scale * rw[c]);
  }
}

extern "C" void kernel_launch(void* const* d_in, const int* in_sizes, int n_in,
                              void* d_out, int out_size, void* d_ws, size_t ws_size,
                              hipStream_t stream) {
  (void)in_sizes; (void)n_in; (void)out_size; (void)ws_size;
  const float* x     = (const float*)d_in[0];
  const float* ln_w  = (const float*)d_in[1];
  const float* ln_b  = (const float*)d_in[2];
  const float* w_in  = (const float*)d_in[3];
  const float* cw    = (const float*)d_in[4];
  const float* cb    = (const float*)d_in[5];
  const float* dtb   = (const float*)d_in[6];
  const float* alog  = (const float*)d_in[7];
  const float* dvec  = (const float*)d_in[8];
  const float* rmsw  = (const float*)d_in[9];
  const float* w_out = (const float*)d_in[10];
  float* out = (float*)d_out;

  // Workspace budget: known-good high-water 253.8 MB. Total here ~241 MB.
  // REGION hosts LN fp16 (ln->gemm1) then Yf fp32 (scan->gate). G overlays Zb.
  // XT overlays XPRE (XPRE dead after conv; XT written after conv from XH).
  char* ws = (char*)d_ws;
  size_t off = 0;
  auto alloc = [&](size_t bytes) -> char* {
    char* p = ws + off;
    off += (bytes + 255) & ~(size_t)255;
    return p;
  };
  _Float16* W1 = (_Float16*)alloc(2ull * 2 * NPAD1 * 1024);   // 17.8 MB
  _Float16* W2 = (_Float16*)alloc(2ull * 2 * 1024 * 2048);    //  8.4 MB
  char* REGION = alloc(4ull * BL * D_INNER);                  // 67.1 MB
  _Float16* LNf = (_Float16*)REGION;
  float* Yf = (float*)REGION;
  _Float16* Zb = (_Float16*)alloc(2ull * BL * D_INNER);       // 33.6 MB
  _Float16* XPRE = (_Float16*)alloc(2ull * BL * D_INNER);     // 33.6 MB (reused as XT)
  _Float16* XT = XPRE;
  _Float16* XH = (_Float16*)alloc(2ull * BL * D_INNER);       // 33.6 MB
  float* AUX  = (float*)alloc(4ull * BL * 160);               //  5.2 MB
  float* BC = (float*)alloc(4ull * BL * D_STATE);             //  2.1 MB
  float* CC = (float*)alloc(4ull * BL * D_STATE);             //  2.1 MB
  float* DTt = (float*)alloc(4ull * NHEADS * BL);             //  1.0 MB
  float* LC  = (float*)alloc(4ull * NHEADS * BL);             //  1.0 MB
  _Float16* BT = (_Float16*)alloc(2ull * D_STATE * BL);       //  1.0 MB
  float* CS = (float*)alloc(4ull * 2 * NHEADS * NCHUNK * 4096); // 33.6 MB

  cvt_w1_kernel<<<(2 * NPAD1 * 1024) / 256, 256, 0, stream>>>(w_in, W1);
  cvt_w2_kernel<<<(2 * 1024 * 2048) / 256, 256, 0, stream>>>(w_out, W2);

  for (int layer = 0; layer < 2; ++layer) {
    const float* hin = layer ? (const float*)out : x;
    size_t o1 = (size_t)layer * NPAD1 * 1024;
    size_t o2 = (size_t)layer * 1024 * 2048;
    ln_kernel<<<BL, 256, 0, stream>>>(hin, ln_w + layer * D_MODEL, ln_b + layer * D_MODEL, LNf);
    gemm_f16_kernel<0><<<dim3((8192 / 256) * (NPAD1 / 256)), 512, 0, stream>>>(
        LNf, 1024, W1 + o1, 1024, NPAD1 / 256, Zb, XPRE, AUX, nullptr, nullptr);
    dtlc_kernel<<<2048, 128, 0, stream>>>(AUX, dtb + layer * NHEADS,
                                          alog + layer * NHEADS, DTt, LC);
    conv_kernel<<<dim3(BL / 16, 9), 256, 0, stream>>>(XPRE, AUX, cw + layer * CONV_DIM * 4,
                                                      cb + layer * CONV_DIM, XH, BC, CC);
    transpose_x_kernel<<<dim3(32, 128), 256, 0, stream>>>(XH, XT);
    transpose_b_kernel<<<128, 256, 0, stream>>>(BC, BT);
    scan_state_kernel<<<2048, 256, 0, stream>>>(XT, BT, LC, DTt, CS);
    scan_p2_kernel<<<256, 256, 0, stream>>>(CS, LC);
    scan_y_kernel<<<2048, 256, 0, stream>>>(XT, CC, BC, CS, LC, DTt,
                                            dvec + layer * NHEADS, Yf);
    gate_rms_kernel<<<BL, 256, 0, stream>>>(Yf, Zb, rmsw + layer * D_INNER, Zb);
    gemm_f16_kernel<1><<<dim3((8192 / 256) * (1024 / 256)), 512, 0, stream>>>(
        Zb, 2048, W2 + o2, 2048, 1024 / 256, nullptr, nullptr, nullptr, out, hin);
  }
}

// Round 6
// 743.701 us; speedup vs baseline: 1.0822x; 1.0822x over previous
//
#include <hip/hip_runtime.h>
#include <stdint.h>

#define D_MODEL   1024
#define D_STATE   64
#define D_INNER   2048
#define NHEADS    32
#define CONV_DIM  2176
#define D_IN_PROJ 4256
#define NPAD1     4352   // 34*128, padded N for in_proj GEMM
#define LSEQ      4096
#define BL        8192   // B*L
#define NCHUNK    32     // scan time-chunks
#define TCH       128    // steps per chunk
#define EPS       1e-5f

typedef __attribute__((ext_vector_type(8))) _Float16 f16x8;
typedef __attribute__((ext_vector_type(4))) _Float16 f16x4;
typedef __attribute__((ext_vector_type(4))) float f32x4;

__device__ __forceinline__ void load_lds16(const void* g, void* l) {
  __builtin_amdgcn_global_load_lds((const __attribute__((address_space(1))) void*)g,
                                   (__attribute__((address_space(3))) void*)l, 16, 0, 0);
}

// ---------------- weight casts: fp32 -> fp16 ----------------
__global__ __launch_bounds__(256) void cvt_w1_kernel(const float* __restrict__ w,
                                                     _Float16* __restrict__ o) {
  size_t idx = (size_t)blockIdx.x * 256 + threadIdx.x;   // over 2*4352*1024
  int k = idx & 1023;
  size_t nr = idx >> 10;
  int layer = (int)(nr / NPAD1);
  int n = (int)(nr % NPAD1);
  float v = (n < D_IN_PROJ) ? w[((size_t)layer * D_IN_PROJ + n) * 1024 + k] : 0.f;
  o[idx] = (_Float16)v;
}
__global__ __launch_bounds__(256) void cvt_w2_kernel(const float* __restrict__ w,
                                                     _Float16* __restrict__ o) {
  size_t idx = (size_t)blockIdx.x * 256 + threadIdx.x;   // over 2*1024*2048
  o[idx] = (_Float16)w[idx];
}

// ---------------- layernorm (row of 1024), fp32 in -> fp16 out ----------------
__global__ __launch_bounds__(256) void ln_kernel(const float* __restrict__ x,
                                                 const float* __restrict__ w,
                                                 const float* __restrict__ b,
                                                 _Float16* __restrict__ o) {
  int row = blockIdx.x, tid = threadIdx.x;
  const float* xr = x + (size_t)row * D_MODEL;
  float4 v = *(const float4*)(xr + tid * 4);
  float s = v.x + v.y + v.z + v.w;
  float q = v.x * v.x + v.y * v.y + v.z * v.z + v.w * v.w;
  for (int off = 1; off < 64; off <<= 1) { s += __shfl_xor(s, off); q += __shfl_xor(q, off); }
  __shared__ float rs[4], rq[4];
  int wave = tid >> 6, lane = tid & 63;
  if (lane == 0) { rs[wave] = s; rq[wave] = q; }
  __syncthreads();
  s = rs[0] + rs[1] + rs[2] + rs[3];
  q = rq[0] + rq[1] + rq[2] + rq[3];
  float mean = s * (1.f / D_MODEL);
  float var = q * (1.f / D_MODEL) - mean * mean;
  float rstd = rsqrtf(var + EPS);
  int c = tid * 4;
  f16x4 ov;
  ov[0] = (_Float16)((v.x - mean) * rstd * w[c + 0] + b[c + 0]);
  ov[1] = (_Float16)((v.y - mean) * rstd * w[c + 1] + b[c + 1]);
  ov[2] = (_Float16)((v.z - mean) * rstd * w[c + 2] + b[c + 2]);
  ov[3] = (_Float16)((v.w - mean) * rstd * w[c + 3] + b[c + 3]);
  *(f16x4*)(o + (size_t)row * D_MODEL + c) = ov;
}

// ---------------- fp16 GEMM, C[m,n] = sum_k A[m,k]*B[n,k] ----------------
// 256x128 tile, BK=32, 8 waves (wave = 64x64 quadrant, 4x4 frags).
// TRIPLE-buffered, counted-vmcnt: tile k's loads issued 2 K-steps before use
// (vmcnt(6) waits only tile k; 9 loads max in flight). LDS slot-XOR swizzle
// (slot ^= (row>>1)&3) on BOTH sides (rule #21). XCD-chunked band raster.
// NOTE (R2-R4): 2-buf/3-buf/4-buf-phased all measure 129+-1 us, MfmaUtil 23-25%.
// Limiter is NOT pipeline depth; keeping this (best occupancy + exact-256 grid
// for MODE 1) until the real limiter is identified from disasm.
template <int MODE>
__global__ __launch_bounds__(512, 4) void gemm_f16_kernel(
    const _Float16* __restrict__ A, int lda,
    const _Float16* __restrict__ Bw, int K, int NBN,
    _Float16* __restrict__ Zb, _Float16* __restrict__ XPRE, float* __restrict__ AUX,
    float* __restrict__ Cf, const float* __restrict__ resid) {
  __shared__ _Float16 lA[3][256 * 32];
  __shared__ _Float16 lB[3][128 * 32];
  int tid = threadIdx.x;
  int wv = tid >> 6, lane = tid & 63;
  // XCD-chunked bijection (nwg % 8 == 0) + band raster
  int nwg = gridDim.x;
  int cpx = nwg >> 3;
  int wg = ((int)blockIdx.x & 7) * cpx + ((int)blockIdx.x >> 3);
  int band = wg / (4 * NBN), rem = wg % (4 * NBN);
  int bm = band * 4 + (rem & 3);
  int bn = rem >> 2;

  const int wm = (wv >> 1) * 64, wn = (wv & 1) * 64;
  const int fr = lane & 15;
  const int s4 = lane >> 4;           // 16B slot within 64B row
  size_t aoff = (size_t)(bm * 256) * lda;
  size_t boff = (size_t)(bn * 128) * K;

  f32x4 acc[4][4];
  f32x4 zero = {0.f, 0.f, 0.f, 0.f};
#pragma unroll
  for (int i = 0; i < 4; ++i)
#pragma unroll
    for (int j = 0; j < 4; ++j) acc[i][j] = zero;

  auto stage = [&](int k0, int buf) {
#pragma unroll
    for (int c = 0; c < 2; ++c) {
      int row = (wv * 2 + c) * 16 + (lane >> 2);
      int col = k0 + (((lane & 3) ^ ((row >> 1) & 3)) << 3);   // pre-swizzled source
      load_lds16(A + aoff + (size_t)row * lda + col,
                 &lA[buf][(wv * 2 + c) * 512 + lane * 8]);     // dest lane-linear
    }
    int rowb = wv * 16 + (lane >> 2);
    int colb = k0 + (((lane & 3) ^ ((rowb >> 1) & 3)) << 3);
    load_lds16(Bw + boff + (size_t)rowb * K + colb, &lB[buf][wv * 512 + lane * 8]);
  };

  int nk = K >> 5;
  stage(0, 0);                                    // 3 loads in flight
  stage(32, 1);                                   // 6 in flight
  int cur = 0;
  for (int kk = 0; kk < nk; ++kk) {
    if (kk + 2 < nk) {
      int sb = cur + 2; if (sb >= 3) sb -= 3;
      stage((kk + 2) << 5, sb);                   // 9 in flight
      asm volatile("s_waitcnt vmcnt(6)" ::: "memory");  // tile kk retired
    } else if (kk + 1 < nk) {
      asm volatile("s_waitcnt vmcnt(3)" ::: "memory");
    } else {
      asm volatile("s_waitcnt vmcnt(0)" ::: "memory");
    }
    __builtin_amdgcn_s_barrier();
    __builtin_amdgcn_sched_barrier(0);
    f16x8 af[4], bf[4];
#pragma unroll
    for (int i = 0; i < 4; ++i) {
      int R = wm + i * 16 + fr;
      af[i] = *(const f16x8*)&lA[cur][R * 32 + ((s4 ^ ((R >> 1) & 3)) << 3)];
    }
#pragma unroll
    for (int j = 0; j < 4; ++j) {
      int R = wn + j * 16 + fr;
      bf[j] = *(const f16x8*)&lB[cur][R * 32 + ((s4 ^ ((R >> 1) & 3)) << 3)];
    }
#pragma unroll
    for (int i = 0; i < 4; ++i)
#pragma unroll
      for (int j = 0; j < 4; ++j)
        acc[i][j] = __builtin_amdgcn_mfma_f32_16x16x32_f16(af[i], bf[j], acc[i][j], 0, 0, 0);
    __builtin_amdgcn_sched_barrier(0);
    __builtin_amdgcn_s_barrier();                 // cur fully read; safe to overwrite
    cur = cur + 1; if (cur >= 3) cur = 0;
  }

  int r0 = (lane >> 4) * 4;
  int cc = lane & 15;
#pragma unroll
  for (int i = 0; i < 4; ++i) {
#pragma unroll
    for (int j = 0; j < 4; ++j) {
      int col = bn * 128 + wn + j * 16 + cc;
#pragma unroll
      for (int r = 0; r < 4; ++r) {
        size_t row = (size_t)(bm * 256 + wm + i * 16 + r0 + r);
        float v = acc[i][j][r];
        if constexpr (MODE == 0) {
          if (col < 2048)       Zb[row * 2048 + col] = (_Float16)v;
          else if (col < 4096)  XPRE[row * 2048 + (col - 2048)] = (_Float16)v;
          else if (col < 4256)  AUX[row * 160 + (col - 4096)] = v;
        } else {
          size_t idx = row * 1024 + col;
          Cf[idx] = v + resid[idx];
        }
      }
    }
  }
}

// ---------------- fused dt: softplus(dt_raw+dt_bias), dta=dt*A, chunk cumsum ----------------
// one block (128 thr) per (h,b,chunk): wave shuffle-scan + cross-wave fixup
__global__ __launch_bounds__(128) void dtlc_kernel(const float* __restrict__ aux,
                                                   const float* __restrict__ dtb,
                                                   const float* __restrict__ alog,
                                                   float* __restrict__ dtt,
                                                   float* __restrict__ lco) {
  int bid = blockIdx.x;    // 2048 = (h,b,chunk)
  int h = bid >> 6, b = (bid >> 5) & 1, ct = bid & 31;
  int tid = threadIdx.x, lane = tid & 63;
  int l = b * LSEQ + ct * TCH + tid;                       // row in BL
  float A = -__expf(alog[h]);                              // A = -exp(A_log)
  float v = aux[(size_t)l * 160 + 128 + h] + dtb[h];
  float sp = (v > 20.f) ? v : log1pf(expf(v));
  size_t base = (size_t)h * BL + b * LSEQ + ct * TCH;
  dtt[base + tid] = sp;
  float d = sp * A;                                        // log per-step decay <= 0
#pragma unroll
  for (int off = 1; off < 64; off <<= 1) {
    float o = __shfl_up(d, off);
    if (lane >= off) d += o;
  }
  __shared__ float tot;
  if (tid == 63) tot = d;
  __syncthreads();
  if (tid >= 64) d += tot;
  lco[base + tid] = d;
}

// ---------------- causal depthwise conv (width 4) + bias + silu + FUSED transposes --------
// tiled: 16 timesteps per block, rolling register window. Each thread owns one
// channel x 16 steps -> registers already hold the transposed layout: write
// XT[c][l0..l0+15] / BT[n][l0..l0+15] directly (f16x8 x2). B/C also written
// row-major fp32 for scan_y. Eliminates transpose_x/transpose_b kernels + XH.
__global__ __launch_bounds__(256) void conv_kernel(const _Float16* __restrict__ xpre,
                                                   const float* __restrict__ aux,
                                                   const float* __restrict__ cw,
                                                   const float* __restrict__ cb,
                                                   _Float16* __restrict__ xt,
                                                   float* __restrict__ Bo,
                                                   float* __restrict__ Co,
                                                   _Float16* __restrict__ bt) {
  int c = blockIdx.y * 256 + threadIdx.x;
  if (c >= CONV_DIM) return;
  int l0 = blockIdx.x * 16;                 // 512 blocks in x; 4096 % 16 == 0
  float w0 = cw[c * 4 + 0], w1 = cw[c * 4 + 1], w2 = cw[c * 4 + 2], w3 = cw[c * 4 + 3];
  float bias = cb[c];
  bool isx = (c < 2048);
  auto ldx = [&](int l) -> float {
    return isx ? (float)xpre[(size_t)l * 2048 + c] : aux[(size_t)l * 160 + (c - 2048)];
  };
  float a0 = 0.f, a1 = 0.f, a2 = 0.f;
  if ((l0 & 4095) != 0) { a0 = ldx(l0 - 3); a1 = ldx(l0 - 2); a2 = ldx(l0 - 1); }
  _Float16 ob[16];
#pragma unroll
  for (int t = 0; t < 16; ++t) {
    int l = l0 + t;
    float a3 = ldx(l);
    float acc = bias + a0 * w0 + a1 * w1 + a2 * w2 + a3 * w3;
    acc = acc / (1.f + __expf(-acc));       // silu
    ob[t] = (_Float16)acc;
    if (!isx) {
      if (c < 2112) Bo[(size_t)l * 64 + (c - 2048)] = acc;
      else          Co[(size_t)l * 64 + (c - 2112)] = acc;
    }
    a0 = a1; a1 = a2; a2 = a3;
  }
  f16x8 v0, v1;
#pragma unroll
  for (int j = 0; j < 8; ++j) { v0[j] = ob[j]; v1[j] = ob[8 + j]; }
  if (isx) {
    *(f16x8*)&xt[(size_t)c * 8192 + l0] = v0;
    *(f16x8*)&xt[(size_t)c * 8192 + l0 + 8] = v1;
  } else if (c < 2112) {
    *(f16x8*)&bt[(size_t)(c - 2048) * 8192 + l0] = v0;
    *(f16x8*)&bt[(size_t)(c - 2048) * 8192 + l0 + 8] = v1;
  }
}

// ---------------- SSD pass 1 (MFMA): per-chunk local end-state ----------------
// S_loc[p][n] = sum_t (dt_t*exp(lc_last-lc_t)*X[t,p]) * B[t,n]; grid 2048 = (b,h,chunk).
__global__ __launch_bounds__(256) void scan_state_kernel(
    const _Float16* __restrict__ xt, const _Float16* __restrict__ bt,
    const float* __restrict__ lc, const float* __restrict__ dtt,
    float* __restrict__ cs) {
  int bid = blockIdx.x;
  int chunk = bid & 31, h = (bid >> 5) & 31, b = bid >> 10;
  int tid = threadIdx.x;
  size_t gb = (size_t)b * LSEQ + chunk * TCH;
  size_t cdb = (size_t)h * BL + gb;
  __shared__ _Float16 xtl[64 * 128];   // [p][t], swizzled
  __shared__ _Float16 btl[64 * 128];   // [n][t], swizzled
  __shared__ float ldsW[128];
  if (tid < 128) ldsW[tid] = dtt[cdb + tid] * __expf(lc[cdb + 127] - lc[cdb + tid]);
  __syncthreads();
  int rr = tid >> 4, cl = tid & 15;
#pragma unroll
  for (int p = 0; p < 4; ++p) {
    int row = p * 16 + rr;
    f16x8 v = *(const f16x8*)&xt[(size_t)(h * 64 + row) * BL + gb + cl * 8];
    f16x8 bv = *(const f16x8*)&bt[(size_t)row * BL + gb + cl * 8];
    f16x8 sv;
#pragma unroll
    for (int j = 0; j < 8; ++j) sv[j] = (_Float16)((float)v[j] * ldsW[cl * 8 + j]);
    int byo = (row * 256 + cl * 16) ^ ((row & 7) << 4);
    *(f16x8*)((char*)xtl + byo) = sv;
    *(f16x8*)((char*)btl + byo) = bv;
  }
  __syncthreads();
  int wv = tid >> 6, lane = tid & 63;
  int fr = lane & 15, fk = (lane >> 4) * 8, r0 = (lane >> 4) * 4, cc = lane & 15;
  int swz = (fr & 7) << 4;
  f32x4 acc[4];
  f32x4 zero = {0.f, 0.f, 0.f, 0.f};
#pragma unroll
  for (int j = 0; j < 4; ++j) acc[j] = zero;
#pragma unroll
  for (int k0 = 0; k0 < 128; k0 += 32) {
    f16x8 af = *(const f16x8*)((char*)xtl + (((wv * 16 + fr) * 256 + (k0 + fk) * 2) ^ swz));
#pragma unroll
    for (int j = 0; j < 4; ++j) {
      f16x8 bf = *(const f16x8*)((char*)btl + (((j * 16 + fr) * 256 + (k0 + fk) * 2) ^ swz));
      acc[j] = __builtin_amdgcn_mfma_f32_16x16x32_f16(af, bf, acc[j], 0, 0, 0);
    }
  }
  size_t cbase = (((size_t)(b * 32 + h) * 32) + chunk) * 4096;
#pragma unroll
  for (int j = 0; j < 4; ++j)
#pragma unroll
    for (int r = 0; r < 4; ++r)
      cs[cbase + (wv * 16 + r0 + r) * 64 + j * 16 + cc] = acc[j][r];
}

// ---------------- scan pass 2: prefix over chunks, IN PLACE (E_c -> S_{c-1}) ----------------
__global__ __launch_bounds__(256) void scan_p2_kernel(float* __restrict__ cs,
                                                      const float* __restrict__ lc) {
  int bid = blockIdx.x;    // (b,h,pq)
  int b = bid >> 7, h = (bid >> 2) & 31, pq = bid & 3;
  int tid = threadIdx.x;
  size_t base = ((size_t)(b * 32 + h) * 32) * 4096 + (size_t)(pq * 256 + tid) * 4;
  const float* lcd = lc + (size_t)h * BL + b * LSEQ;
  float4 s = {0.f, 0.f, 0.f, 0.f};
  for (int c = 0; c < NCHUNK; ++c) {
    size_t idx = base + (size_t)c * 4096;
    float4 e = *(const float4*)&cs[idx];
    float P = __expf(lcd[c * TCH + TCH - 1]);   // total decay of chunk c
    *(float4*)&cs[idx] = s;                     // prefix state entering chunk c
    s.x = e.x + P * s.x;
    s.y = e.y + P * s.y;
    s.z = e.z + P * s.z;
    s.w = e.w + P * s.w;
  }
}

// ---------------- SSD pass 3 (MFMA): Y = (mask o C.B^T).X + exp(lc)*(C.Sprev^T) -----------
// mask[t,s] = exp(lc_t - lc_s)*dt_s for s<=t; diag += D_h (absorbs skip). grid 2048.
// Y output is fp16 (feeds gate+RMSnorm which renormalizes).
__global__ __launch_bounds__(256) void scan_y_kernel(
    const _Float16* __restrict__ xt, const float* __restrict__ Cc,
    const float* __restrict__ Bc, const float* __restrict__ cs,
    const float* __restrict__ lc, const float* __restrict__ dtt,
    const float* __restrict__ Dv, _Float16* __restrict__ y) {
  int bid = blockIdx.x;
  int chunk = bid & 31, h = (bid >> 5) & 31, b = bid >> 10;
  int tid = threadIdx.x;
  size_t gb = (size_t)b * LSEQ + chunk * TCH;
  size_t cdb = (size_t)h * BL + gb;

  __shared__ _Float16 uCB[2 * 128 * 64];   // C [128][64] | B [128][64]; then P [128][128]
  __shared__ _Float16 xtl[64 * 128];       // X^T [p][t]
  __shared__ _Float16 spl[64 * 64];        // Sprev [p][n]
  __shared__ float ldsLc[128];
  __shared__ float ldsDt[128];
  _Float16* Cl = uCB;
  _Float16* Bl = uCB + 128 * 64;
  _Float16* Pl = uCB;

  int rr = tid >> 4, cl = tid & 15;
#pragma unroll
  for (int p = 0; p < 8; ++p) {
    int row = p * 16 + rr;
    float4 cv = *(const float4*)&Cc[(gb + row) * 64 + cl * 4];
    float4 bv = *(const float4*)&Bc[(gb + row) * 64 + cl * 4];
    f16x4 ch = {(_Float16)cv.x, (_Float16)cv.y, (_Float16)cv.z, (_Float16)cv.w};
    f16x4 bh = {(_Float16)bv.x, (_Float16)bv.y, (_Float16)bv.z, (_Float16)bv.w};
    int byo = (row * 128 + cl * 8) ^ ((row & 7) << 4);
    *(f16x4*)((char*)Cl + byo) = ch;
    *(f16x4*)((char*)Bl + byo) = bh;
  }
  size_t cbase = (((size_t)(b * 32 + h) * 32) + chunk) * 4096;
#pragma unroll
  for (int p = 0; p < 4; ++p) {
    int row = p * 16 + rr;
    f16x8 v = *(const f16x8*)&xt[(size_t)(h * 64 + row) * BL + gb + cl * 8];
    int byo = (row * 256 + cl * 16) ^ ((row & 7) << 4);
    *(f16x8*)((char*)xtl + byo) = v;
    float4 sv = *(const float4*)&cs[cbase + row * 64 + cl * 4];
    f16x4 sh = {(_Float16)sv.x, (_Float16)sv.y, (_Float16)sv.z, (_Float16)sv.w};
    int byo2 = (row * 128 + cl * 8) ^ ((row & 7) << 4);
    *(f16x4*)((char*)spl + byo2) = sh;
  }
  if (tid < 128) { ldsLc[tid] = lc[cdb + tid]; ldsDt[tid] = dtt[cdb + tid]; }
  __syncthreads();

  int wv = tid >> 6, lane = tid & 63;
  int fr = lane & 15, fk = (lane >> 4) * 8, r0 = (lane >> 4) * 4, cc = lane & 15;
  int tb = wv * 32;                 // this wave's 32 output rows (t)
  int swz = (fr & 7) << 4;

  f32x4 accY[2][4];                 // [t-tile][p-tile]
  f32x4 accS[2][8];                 // [t-tile][s-tile]
  f32x4 zero = {0.f, 0.f, 0.f, 0.f};
#pragma unroll
  for (int i = 0; i < 2; ++i) {
#pragma unroll
    for (int j = 0; j < 4; ++j) accY[i][j] = zero;
#pragma unroll
    for (int j = 0; j < 8; ++j) accS[i][j] = zero;
  }

  // phase 1+2: inter-term C.Sprev^T and S1 = C.B^T (K = n = 64)
#pragma unroll
  for (int k0 = 0; k0 < 64; k0 += 32) {
    f16x8 ac[2];
#pragma unroll
    for (int i = 0; i < 2; ++i)
      ac[i] = *(const f16x8*)((char*)Cl + (((tb + i * 16 + fr) * 128 + (k0 + fk) * 2) ^ swz));
#pragma unroll
    for (int j = 0; j < 4; ++j) {
      f16x8 bs = *(const f16x8*)((char*)spl + (((j * 16 + fr) * 128 + (k0 + fk) * 2) ^ swz));
#pragma unroll
      for (int i = 0; i < 2; ++i)
        accY[i][j] = __builtin_amdgcn_mfma_f32_16x16x32_f16(ac[i], bs, accY[i][j], 0, 0, 0);
    }
#pragma unroll
    for (int j = 0; j < 8; ++j) {
      f16x8 bb = *(const f16x8*)((char*)Bl + (((j * 16 + fr) * 128 + (k0 + fk) * 2) ^ swz));
#pragma unroll
      for (int i = 0; i < 2; ++i)
        accS[i][j] = __builtin_amdgcn_mfma_f32_16x16x32_f16(ac[i], bb, accS[i][j], 0, 0, 0);
    }
  }

  // scale inter-term by exp(lc_t)
  float lct[2][4];
#pragma unroll
  for (int i = 0; i < 2; ++i)
#pragma unroll
    for (int r = 0; r < 4; ++r) lct[i][r] = ldsLc[tb + i * 16 + r0 + r];
#pragma unroll
  for (int i = 0; i < 2; ++i)
#pragma unroll
    for (int r = 0; r < 4; ++r) {
      float sc = __expf(lct[i][r]);
#pragma unroll
      for (int j = 0; j < 4; ++j) accY[i][j][r] *= sc;
    }

  __syncthreads();   // all waves done reading Cl/Bl/spl before P overlays C|B
  float Dh = Dv[h];
#pragma unroll
  for (int i = 0; i < 2; ++i)
#pragma unroll
    for (int jj = 0; jj < 8; ++jj) {
      int s = jj * 16 + cc;
      float lcs = ldsLc[s];
      float dts = ldsDt[s];
#pragma unroll
      for (int r = 0; r < 4; ++r) {
        int t = tb + i * 16 + r0 + r;
        float v = 0.f;
        if (s <= t) v = accS[i][jj][r] * __expf(lct[i][r] - lcs) * dts;
        if (s == t) v += Dh;                       // skip term: P diag += D_h
        int byo = (t * 256 + s * 2) ^ ((t & 7) << 4);
        *(_Float16*)((char*)Pl + byo) = (_Float16)v;
      }
    }
  __syncthreads();

  // phase 4: Y += P @ X  (K = s = 128)
#pragma unroll
  for (int k0 = 0; k0 < 128; k0 += 32) {
    f16x8 ap[2];
#pragma unroll
    for (int i = 0; i < 2; ++i)
      ap[i] = *(const f16x8*)((char*)Pl + (((tb + i * 16 + fr) * 256 + (k0 + fk) * 2) ^ swz));
#pragma unroll
    for (int j = 0; j < 4; ++j) {
      f16x8 bx = *(const f16x8*)((char*)xtl + (((j * 16 + fr) * 256 + (k0 + fk) * 2) ^ swz));
#pragma unroll
      for (int i = 0; i < 2; ++i)
        accY[i][j] = __builtin_amdgcn_mfma_f32_16x16x32_f16(ap[i], bx, accY[i][j], 0, 0, 0);
    }
  }

#pragma unroll
  for (int i = 0; i < 2; ++i)
#pragma unroll
    for (int j = 0; j < 4; ++j)
#pragma unroll
      for (int r = 0; r < 4; ++r) {
        int t = tb + i * 16 + r0 + r;
        y[(gb + t) * 2048 + h * 64 + j * 16 + cc] = (_Float16)accY[i][j][r];
      }
}

// ---------------- gate (y * silu(z)) + RMSNorm * rms_w -> fp16 G, IN PLACE over Zb ----------
// vectorized: thread owns 8 contiguous cols (f16x8 loads/stores)
__global__ __launch_bounds__(256) void gate_rms_kernel(const _Float16* __restrict__ yf,
                                                       const _Float16* __restrict__ zb,
                                                       const float* __restrict__ rw,
                                                       _Float16* __restrict__ g) {
  int row = blockIdx.x, tid = threadIdx.x;
  int c0 = tid * 8;
  f16x8 yv = *(const f16x8*)(yf + (size_t)row * D_INNER + c0);
  f16x8 zv = *(const f16x8*)(zb + (size_t)row * D_INNER + c0);
  float gv[8];
  float q = 0.f;
#pragma unroll
  for (int u = 0; u < 8; ++u) {
    float yy = (float)yv[u];
    float zz = (float)zv[u];
    float t = yy * (zz / (1.f + __expf(-zz)));
    gv[u] = t;
    q += t * t;
  }
  for (int off = 1; off < 64; off <<= 1) q += __shfl_xor(q, off);
  __shared__ float rq[4];
  if ((tid & 63) == 0) rq[tid >> 6] = q;
  __syncthreads();    // all reads of this row are done before writes below
  q = rq[0] + rq[1] + rq[2] + rq[3];
  float scale = rsqrtf(q * (1.f / D_INNER) + EPS);
  float4 r0 = *(const float4*)&rw[c0];
  float4 r1 = *(const float4*)&rw[c0 + 4];
  f16x8 o;
  o[0] = (_Float16)(gv[0] * scale * r0.x);
  o[1] = (_Float16)(gv[1] * scale * r0.y);
  o[2] = (_Float16)(gv[2] * scale * r0.z);
  o[3] = (_Float16)(gv[3] * scale * r0.w);
  o[4] = (_Float16)(gv[4] * scale * r1.x);
  o[5] = (_Float16)(gv[5] * scale * r1.y);
  o[6] = (_Float16)(gv[6] * scale * r1.z);
  o[7] = (_Float16)(gv[7] * scale * r1.w);
  *(f16x8*)(g + (size_t)row * D_INNER + c0) = o;
}

extern "C" void kernel_launch(void* const* d_in, const int* in_sizes, int n_in,
                              void* d_out, int out_size, void* d_ws, size_t ws_size,
                              hipStream_t stream) {
  (void)in_sizes; (void)n_in; (void)out_size; (void)ws_size;
  const float* x     = (const float*)d_in[0];
  const float* ln_w  = (const float*)d_in[1];
  const float* ln_b  = (const float*)d_in[2];
  const float* w_in  = (const float*)d_in[3];
  const float* cw    = (const float*)d_in[4];
  const float* cb    = (const float*)d_in[5];
  const float* dtb   = (const float*)d_in[6];
  const float* alog  = (const float*)d_in[7];
  const float* dvec  = (const float*)d_in[8];
  const float* rmsw  = (const float*)d_in[9];
  const float* w_out = (const float*)d_in[10];
  float* out = (float*)d_out;

  // Workspace budget: known-good high-water 253.8 MB. Total here ~241 MB.
  // REGION hosts LN fp16 (ln->gemm1) then Yf fp16 (scan->gate). G overlays Zb.
  // XT lives in the old XH slot (conv reads XPRE, writes XT -- no alias).
  char* ws = (char*)d_ws;
  size_t off = 0;
  auto alloc = [&](size_t bytes) -> char* {
    char* p = ws + off;
    off += (bytes + 255) & ~(size_t)255;
    return p;
  };
  _Float16* W1 = (_Float16*)alloc(2ull * 2 * NPAD1 * 1024);   // 17.8 MB
  _Float16* W2 = (_Float16*)alloc(2ull * 2 * 1024 * 2048);    //  8.4 MB
  char* REGION = alloc(4ull * BL * D_INNER);                  // 67.1 MB
  _Float16* LNf = (_Float16*)REGION;
  _Float16* Yf = (_Float16*)REGION;
  _Float16* Zb = (_Float16*)alloc(2ull * BL * D_INNER);       // 33.6 MB
  _Float16* XPRE = (_Float16*)alloc(2ull * BL * D_INNER);     // 33.6 MB
  _Float16* XT = (_Float16*)alloc(2ull * BL * D_INNER);       // 33.6 MB (old XH slot)
  float* AUX  = (float*)alloc(4ull * BL * 160);               //  5.2 MB
  float* BC = (float*)alloc(4ull * BL * D_STATE);             //  2.1 MB
  float* CC = (float*)alloc(4ull * BL * D_STATE);             //  2.1 MB
  float* DTt = (float*)alloc(4ull * NHEADS * BL);             //  1.0 MB
  float* LC  = (float*)alloc(4ull * NHEADS * BL);             //  1.0 MB
  _Float16* BT = (_Float16*)alloc(2ull * D_STATE * BL);       //  1.0 MB
  float* CS = (float*)alloc(4ull * 2 * NHEADS * NCHUNK * 4096); // 33.6 MB

  cvt_w1_kernel<<<(2 * NPAD1 * 1024) / 256, 256, 0, stream>>>(w_in, W1);
  cvt_w2_kernel<<<(2 * 1024 * 2048) / 256, 256, 0, stream>>>(w_out, W2);

  for (int layer = 0; layer < 2; ++layer) {
    const float* hin = layer ? (const float*)out : x;
    size_t o1 = (size_t)layer * NPAD1 * 1024;
    size_t o2 = (size_t)layer * 1024 * 2048;
    ln_kernel<<<BL, 256, 0, stream>>>(hin, ln_w + layer * D_MODEL, ln_b + layer * D_MODEL, LNf);
    gemm_f16_kernel<0><<<dim3((8192 / 256) * (NPAD1 / 128)), 512, 0, stream>>>(
        LNf, 1024, W1 + o1, 1024, NPAD1 / 128, Zb, XPRE, AUX, nullptr, nullptr);
    dtlc_kernel<<<2048, 128, 0, stream>>>(AUX, dtb + layer * NHEADS,
                                          alog + layer * NHEADS, DTt, LC);
    conv_kernel<<<dim3(BL / 16, 9), 256, 0, stream>>>(XPRE, AUX, cw + layer * CONV_DIM * 4,
                                                      cb + layer * CONV_DIM, XT, BC, CC, BT);
    scan_state_kernel<<<2048, 256, 0, stream>>>(XT, BT, LC, DTt, CS);
    scan_p2_kernel<<<256, 256, 0, stream>>>(CS, LC);
    scan_y_kernel<<<2048, 256, 0, stream>>>(XT, CC, BC, CS, LC, DTt,
                                            dvec + layer * NHEADS, Yf);
    gate_rms_kernel<<<BL, 256, 0, stream>>>(Yf, Zb, rmsw + layer * D_INNER, Zb);
    gemm_f16_kernel<1><<<dim3((8192 / 256) * (1024 / 128)), 512, 0, stream>>>(
        Zb, 2048, W2 + o2, 2048, 1024 / 128, nullptr, nullptr, nullptr, out, hin);
  }
}